// Round 2
// baseline (802.937 us; speedup 1.0000x reference)
//
#include <hip/hip_runtime.h>
#include <hip/hip_bf16.h>

typedef __bf16 bf16x8 __attribute__((ext_vector_type(8)));
typedef __bf16 bf16x4 __attribute__((ext_vector_type(4)));
typedef float  f32x4  __attribute__((ext_vector_type(4)));

#define QL 1024
#define NH 32
#define NKV 8
#define HD 128
#define KVLEN 2048
#define QKV_LD 6144

// async global->LDS, 16B per lane. LDS dest = wave-uniform base + lane*16;
// we pass per-lane ptr = base + lane*16 so both interpretations agree.
// Global side addressing is per-lane (gather is allowed on the global side).
typedef const __attribute__((address_space(1))) void gv_t;
typedef __attribute__((address_space(3))) void lv_t;
__device__ __forceinline__ void gll16(const void* g, void* l) {
  __builtin_amdgcn_global_load_lds((gv_t*)g, (lv_t*)l, 16, 0, 0);
}

// ---------------------------------------------------------------------------
// fp32 -> bf16 plain cast
// ---------------------------------------------------------------------------
__global__ __launch_bounds__(256) void cast_plain(const float* __restrict__ in,
                                                  __bf16* __restrict__ out, int n4) {
  int i = blockIdx.x * 256 + threadIdx.x;
  if (i >= n4) return;
  float4 v = ((const float4*)in)[i];
  bf16x4 o;
  o[0] = (__bf16)v.x; o[1] = (__bf16)v.y; o[2] = (__bf16)v.z; o[3] = (__bf16)v.w;
  ((bf16x4*)out)[i] = o;
}

// ---------------------------------------------------------------------------
// fp32 (R x C) -> bf16 (C x R) transpose-cast
// ---------------------------------------------------------------------------
__global__ __launch_bounds__(256) void transpose_cast(const float* __restrict__ in,
                                                      __bf16* __restrict__ out,
                                                      int R, int C) {
  __shared__ __bf16 tile[64][65];
  int r0 = blockIdx.y * 64, c0 = blockIdx.x * 64;
  int t = threadIdx.x;
  int tr = t >> 4, tc = (t & 15) * 4;
#pragma unroll
  for (int pass = 0; pass < 4; pass++) {
    int r = pass * 16 + tr;
    float4 v = *(const float4*)(in + (size_t)(r0 + r) * C + c0 + tc);
    tile[r][tc + 0] = (__bf16)v.x;
    tile[r][tc + 1] = (__bf16)v.y;
    tile[r][tc + 2] = (__bf16)v.z;
    tile[r][tc + 3] = (__bf16)v.w;
  }
  __syncthreads();
#pragma unroll
  for (int pass = 0; pass < 4; pass++) {
    int cc = pass * 16 + tr;
    bf16x4 o;
#pragma unroll
    for (int j = 0; j < 4; j++) o[j] = tile[tc + j][cc];
    *(bf16x4*)(out + (size_t)(c0 + cc) * R + r0 + tc) = o;
  }
}

// ---------------------------------------------------------------------------
// C[M,N] = A[M,K] @ Bt[N,K]^T
// 128(M) x 256(N) tile, BK=64, depth-2 dbuf at k-half granularity.
// Grid: QKV 32x24=768 = 3x256 exact rounds; WO 32x16=512 = 2x256 exact rounds
// (eliminates the 1.5-round tail that cost 25% at 256^2 tiles).
// 8 waves (2M x 4N), per-wave output 64x64 (acc 4x4 = 64 AGPR).
// 2 phases per K-tile, 16 MFMA + 8 ds_read_b128 + 3 gll16 + 1 barrier each.
// Counted vmcnt(6) (never 0 in steady state); stage units issued 3-4 phases
// before consumption (~2000 cyc lead > 900 cyc HBM latency).
//
// Staging units per K-tile t: Ak0,Ak1 (128x32, 1 load/thr), Bk0,Bk1 (256x32,
// 2 loads/thr). Issue plan: prologue {A0B0(0), A1B1(0), A0B0(1)}; t.P1 issues
// A1B1(t+1); t.P2 issues A0B0(t+2). Queue at any wait <= 9 loads, need all but
// newest 6 -> vmcnt(6). Tail steps 6 -> 3 -> 0.
// Buffer-overwrite safety: each region's writes are >=1 barrier after its last
// reads (P1 writes buf[(t+1)&1].k1, last read (t-1).P2 pre-barrier; P2 writes
// buf[t&1].k0, last read t.P1 pre-barrier).
// LDS swizzle (within k-half): phys slot p = quad ^ ((row>>1)&3), applied on
// the global source of gll16 (LDS dest stays lane-linear) -- same family as
// the measured-0-conflict round-1 layout.
// ---------------------------------------------------------------------------
template <int OUT_BF16>
__global__ __launch_bounds__(512, 2) void gemm128x256(const __bf16* __restrict__ A,
                                                      const __bf16* __restrict__ Bt,
                                                      void* __restrict__ Cout,
                                                      int M, int N, int K) {
  __shared__ __attribute__((aligned(16))) __bf16 sA[2][8192];    // [buf][kh*4096 + r*32 + p*8]
  __shared__ __attribute__((aligned(16))) __bf16 sB[2][16384];   // [buf][kh*8192 + n*32 + p*8]
  const int tid = threadIdx.x;
  const int lane = tid & 63;
  const int wave = tid >> 6;
  const int wm = wave >> 2, wn = wave & 3;   // 2M x 4N
  const int quad = lane >> 4, l16 = lane & 15;

  // XCD-aware bijective swizzle (grids are multiples of 8) + serpentine bx.
  // Chunk/XCD = nwg/8 blocks = 4 full A row-panels (4MB = one XCD L2).
  const int nwg = gridDim.x;
  const int id = blockIdx.x;
  int swz = (id & 7) * (nwg >> 3) + (id >> 3);
  const int gx = N >> 8;
  int by = swz / gx;
  int bx = swz - by * gx;
  if (by & 1) bx = gx - 1 - bx;
  const int row0 = by * 128, col0 = bx * 256;

  // staging: slot s of a k-half: row r=s>>2, phys 16B slot p=s&3 holds logical
  // k-quad q = p ^ ((r>>1)&3) = (s&3)^((s>>3)&3). Thread tid covers slot tid
  // (A: 512 slots) and slots tid, tid+512 (B: 1024 slots).
  const int qsel = (tid & 3) ^ ((tid >> 3) & 3);
  const __bf16* gA  = A  + (size_t)(row0 + (tid >> 2)) * K + qsel * 8;
  const __bf16* gB0 = Bt + (size_t)(col0 + (tid >> 2)) * K + qsel * 8;
  const __bf16* gB1 = gB0 + (size_t)128 * K;

  // read-side: row = ..*16 + l16 -> (row>>1)&3 = (l16>>1)&3
  const int xq = (quad ^ ((l16 >> 1) & 3)) * 8;
  const int abase = (wm * 64 + l16) * 32 + xq;   // + kc*4096 + mt*512
  const int bbase = (wn * 64 + l16) * 32 + xq;   // + kc*8192 + nt*512

  f32x4 acc[4][4];
#pragma unroll
  for (int mt = 0; mt < 4; mt++)
#pragma unroll
    for (int nt = 0; nt < 4; nt++) acc[mt][nt] = (f32x4){0.f, 0.f, 0.f, 0.f};

  const int nT = K >> 6;

#define STAGE_A(t_, kh_)                                                        \
  gll16(gA + (size_t)(t_)*64 + (kh_)*32, &sA[(t_) & 1][(kh_)*4096] + tid * 8)
#define STAGE_B(t_, kh_)                                                        \
  do {                                                                          \
    __bf16* d_ = &sB[(t_) & 1][(kh_)*8192];                                     \
    gll16(gB0 + (size_t)(t_)*64 + (kh_)*32, d_ + tid * 8);                      \
    gll16(gB1 + (size_t)(t_)*64 + (kh_)*32, d_ + 4096 + tid * 8);               \
  } while (0)

  // prologue: 3 bursts of 3 loads; wait all but newest 6 -> tile0.k0 resident
  STAGE_A(0, 0); STAGE_B(0, 0);
  STAGE_A(0, 1); STAGE_B(0, 1);
  if (nT > 1) { STAGE_A(1, 0); STAGE_B(1, 0); }
  asm volatile("s_waitcnt vmcnt(6)" ::: "memory");
  __builtin_amdgcn_s_barrier();

  for (int t = 0; t < nT; ++t) {
    const __bf16* Ab = &sA[t & 1][0];
    const __bf16* Bb = &sB[t & 1][0];
    bf16x8 af[4], bfr[4];

    // ---- phase 1 (kc=0) ----
#pragma unroll
    for (int i = 0; i < 4; ++i) af[i]  = *(const bf16x8*)(Ab + abase + i * 512);
#pragma unroll
    for (int i = 0; i < 4; ++i) bfr[i] = *(const bf16x8*)(Bb + bbase + i * 512);
    if (t + 1 < nT) {
      STAGE_A(t + 1, 1); STAGE_B(t + 1, 1);
      asm volatile("s_waitcnt vmcnt(6)" ::: "memory");
    } else {
      asm volatile("s_waitcnt vmcnt(0)" ::: "memory");
    }
    __builtin_amdgcn_s_barrier();
    __builtin_amdgcn_s_setprio(1);
#pragma unroll
    for (int mt = 0; mt < 4; ++mt)
#pragma unroll
      for (int nt = 0; nt < 4; ++nt)
        acc[mt][nt] = __builtin_amdgcn_mfma_f32_16x16x32_bf16(af[mt], bfr[nt], acc[mt][nt], 0, 0, 0);
    __builtin_amdgcn_s_setprio(0);

    // ---- phase 2 (kc=1) ----
#pragma unroll
    for (int i = 0; i < 4; ++i) af[i]  = *(const bf16x8*)(Ab + 4096 + abase + i * 512);
#pragma unroll
    for (int i = 0; i < 4; ++i) bfr[i] = *(const bf16x8*)(Bb + 8192 + bbase + i * 512);
    if (t + 2 < nT) {
      STAGE_A(t + 2, 0); STAGE_B(t + 2, 0);
      asm volatile("s_waitcnt vmcnt(6)" ::: "memory");
    } else if (t + 1 < nT) {
      asm volatile("s_waitcnt vmcnt(3)" ::: "memory");
    } else {
      asm volatile("" ::: "memory");
    }
    __builtin_amdgcn_s_barrier();
    __builtin_amdgcn_s_setprio(1);
#pragma unroll
    for (int mt = 0; mt < 4; ++mt)
#pragma unroll
      for (int nt = 0; nt < 4; ++nt)
        acc[mt][nt] = __builtin_amdgcn_mfma_f32_16x16x32_bf16(af[mt], bfr[nt], acc[mt][nt], 0, 0, 0);
    __builtin_amdgcn_s_setprio(0);
  }
#undef STAGE_A
#undef STAGE_B

#pragma unroll
  for (int mt = 0; mt < 4; ++mt) {
#pragma unroll
    for (int r = 0; r < 4; ++r) {
      const int grow = row0 + wm * 64 + mt * 16 + quad * 4 + r;
#pragma unroll
      for (int nt = 0; nt < 4; ++nt) {
        const int gcol = col0 + wn * 64 + nt * 16 + l16;
        float v = acc[mt][nt][r];
        if (OUT_BF16)
          ((__bf16*)Cout)[(size_t)grow * N + gcol] = (__bf16)v;
        else
          ((float*)Cout)[(size_t)grow * N + gcol] = v;
      }
    }
  }
}

// ---------------------------------------------------------------------------
// RoPE in-place on qkv
// ---------------------------------------------------------------------------
__global__ __launch_bounds__(256) void rope_kernel(__bf16* __restrict__ qkv) {
  int idx = blockIdx.x * 256 + threadIdx.x;
  int m = idx & 63;
  int rest = idx >> 6;
  int t = rest / 40;
  int head = rest - t * 40;
  int i = t & (QL - 1);
  float pos = (float)(1024 + i);
  float ang = pos * exp2f(-(float)m * 0.31143075889569403f);
  float c = cosf(ang), sn = sinf(ang);
  size_t base = (size_t)t * QKV_LD + head * HD;
  float x0 = (float)qkv[base + m];
  float x1 = (float)qkv[base + 64 + m];
  qkv[base + m]      = (__bf16)(x0 * c - x1 * sn);
  qkv[base + 64 + m] = (__bf16)(x1 * c + x0 * sn);
}

// ---------------------------------------------------------------------------
// k_all[b][kvh][p][d]
// ---------------------------------------------------------------------------
__global__ __launch_bounds__(256) void kv_build_k(const float* __restrict__ kcache,
                                                  const __bf16* __restrict__ qkv,
                                                  __bf16* __restrict__ k_all) {
  int idx = blockIdx.x * 256 + threadIdx.x;
  int d8 = (idx & 15) * 8;
  int p = (idx >> 4) & (KVLEN - 1);
  int bk = idx >> 15;
  int b = bk >> 3, kvh = bk & 7;
  __bf16* dst = k_all + ((size_t)bk * KVLEN + p) * HD + d8;
  if (p < 1024) {
    const float* src = kcache + ((size_t)(b * KVLEN + p) * NKV + kvh) * HD + d8;
    bf16x8 o;
#pragma unroll
    for (int j = 0; j < 8; j++) o[j] = (__bf16)src[j];
    *(bf16x8*)dst = o;
  } else {
    const __bf16* src = qkv + (size_t)(b * QL + p - 1024) * QKV_LD + 4096 + kvh * HD + d8;
    *(bf16x8*)dst = *(const bf16x8*)src;
  }
}

// ---------------------------------------------------------------------------
// v_allT[b][kvh][d][p]
// ---------------------------------------------------------------------------
__global__ __launch_bounds__(256) void kv_build_vT(const float* __restrict__ vcache,
                                                   const __bf16* __restrict__ qkv,
                                                   __bf16* __restrict__ v_allT) {
  __shared__ __bf16 tile[64][130];
  int blk = blockIdx.x;
  int pt = blk & 31, bk = blk >> 5;
  int b = bk >> 3, kvh = bk & 7;
  int p0 = pt * 64;
  int t = threadIdx.x;
  int lr = t >> 4, d8 = (t & 15) * 8;
#pragma unroll
  for (int pass = 0; pass < 4; pass++) {
    int pl = pass * 16 + lr;
    int p = p0 + pl;
    if (p < 1024) {
      const float* src = vcache + ((size_t)(b * KVLEN + p) * NKV + kvh) * HD + d8;
#pragma unroll
      for (int j = 0; j < 8; j++) tile[pl][d8 + j] = (__bf16)src[j];
    } else {
      const __bf16* src = qkv + (size_t)(b * QL + p - 1024) * QKV_LD + 5120 + kvh * HD + d8;
      bf16x8 v = *(const bf16x8*)src;
#pragma unroll
      for (int j = 0; j < 8; j++) tile[pl][d8 + j] = v[j];
    }
  }
  __syncthreads();
#pragma unroll
  for (int pass = 0; pass < 4; pass++) {
    int d = (t >> 3) + pass * 32;
    int ps = (t & 7) * 8;
    bf16x8 o;
#pragma unroll
    for (int j = 0; j < 8; j++) o[j] = tile[ps + j][d];
    *(bf16x8*)(v_allT + ((size_t)bk * HD + d) * KVLEN + p0 + ps) = o;
  }
}

// ---------------------------------------------------------------------------
// Flash attention v3: K/V staged once per block in LDS, shared by 4 GQA waves,
// async gll16 prefetch pipelined across chunks, XOR-swizzled LDS slots.
// ---------------------------------------------------------------------------
__global__ __launch_bounds__(256) void attn_kernel(const __bf16* __restrict__ qkv,
                                                   const __bf16* __restrict__ k_all,
                                                   const __bf16* __restrict__ v_allT,
                                                   __bf16* __restrict__ out) {
  __shared__ __attribute__((aligned(16))) __bf16 sK[64 * 128];   // [key][d], slot-swizzled
  __shared__ __attribute__((aligned(16))) __bf16 sV[128 * 64];   // [d][key], slot-swizzled
  __shared__ __attribute__((aligned(16))) __bf16 sP[4][32 * 72];
  const int tid = threadIdx.x;
  const int lane = tid & 63;
  const int wave = tid >> 6;
  const int quad = lane >> 4, l16 = lane & 15;
  const int bid = blockIdx.x;
  const int b = bid & 3;
  const int kvh = (bid >> 2) & 7;
  const int qt = bid >> 5;
  const int h = kvh * 4 + wave;
  const int i0 = qt * 32;

  const __bf16* kb = k_all + (size_t)(b * NKV + kvh) * KVLEN * HD;
  const __bf16* vb = v_allT + (size_t)(b * NKV + kvh) * HD * KVLEN;

  bf16x8 qf[2][4];
#pragma unroll
  for (int mt = 0; mt < 2; mt++) {
    const __bf16* qb = qkv + (size_t)(b * QL + i0 + mt * 16 + l16) * QKV_LD + h * HD + quad * 8;
#pragma unroll
    for (int kc = 0; kc < 4; kc++) qf[mt][kc] = *(const bf16x8*)(qb + kc * 32);
  }

  int kgo[4], vgo[4];
#pragma unroll
  for (int j = 0; j < 4; j++) {
    int g = wave * 4 + j;
    kgo[j] = (g * 4 + quad) * HD + (l16 ^ (g & 7)) * 8;
    int d = g * 8 + (lane >> 3);
    vgo[j] = d * KVLEN + ((lane & 7) ^ ((lane >> 3) & 7)) * 8;
  }
  __bf16* kls = sK + (wave * 4) * 512 + lane * 8;  // +j*512
  __bf16* vls = sV + (wave * 4) * 512 + lane * 8;

  f32x4 o[8][2];
#pragma unroll
  for (int dt = 0; dt < 8; dt++)
#pragma unroll
    for (int mt = 0; mt < 2; mt++) o[dt][mt] = (f32x4){0.f, 0.f, 0.f, 0.f};
  f32x4 lac[2];
  lac[0] = (f32x4){0.f, 0.f, 0.f, 0.f};
  lac[1] = (f32x4){0.f, 0.f, 0.f, 0.f};

  bf16x8 ones;
#pragma unroll
  for (int j = 0; j < 8; j++) ones[j] = (__bf16)1.0f;

  __bf16* myP = &sP[wave][0];
  const float ES = 0.12751744f;  // (1/sqrt(128)) * log2(e)

  const int cs = (i0 + 1) & ~63;
  const int xsw = l16 & 7;

#pragma unroll
  for (int j = 0; j < 4; j++) gll16(kb + (size_t)cs * HD + kgo[j], kls + j * 512);
#pragma unroll
  for (int j = 0; j < 4; j++) gll16(vb + (size_t)cs + vgo[j], vls + j * 512);

  for (int ci = 0; ci < 17; ci++) {
    const int c = cs + ci * 64;
    __syncthreads();  // A: chunk ci staged; sV safe from prev iter
    f32x4 s[2][4];
#pragma unroll
    for (int nt = 0; nt < 4; nt++) {
      s[0][nt] = (f32x4){0.f, 0.f, 0.f, 0.f};
      s[1][nt] = (f32x4){0.f, 0.f, 0.f, 0.f};
      const __bf16* kp = sK + (4 * l16 + nt) * HD;
#pragma unroll
      for (int kc = 0; kc < 4; kc++) {
        bf16x8 kf = *(const bf16x8*)(kp + ((4 * kc + quad) ^ xsw) * 8);
        s[0][nt] = __builtin_amdgcn_mfma_f32_16x16x32_bf16(qf[0][kc], kf, s[0][nt], 0, 0, 0);
        s[1][nt] = __builtin_amdgcn_mfma_f32_16x16x32_bf16(qf[1][kc], kf, s[1][nt], 0, 0, 0);
      }
    }
    __syncthreads();  // B: all waves done reading sK
    if (ci < 16) {
#pragma unroll
      for (int j = 0; j < 4; j++) gll16(kb + (size_t)(c + 64) * HD + kgo[j], kls + j * 512);
    }
    const bool full = (c >= i0 + 32) && (c <= i0 + 961);
#pragma unroll
    for (int mt = 0; mt < 2; mt++) {
#pragma unroll
      for (int r = 0; r < 4; r++) {
        bf16x4 pk;
        if (full) {
#pragma unroll
          for (int nt = 0; nt < 4; nt++) pk[nt] = (__bf16)exp2f(s[mt][nt][r] * ES);
        } else {
          const int irow = i0 + mt * 16 + quad * 4 + r;
#pragma unroll
          for (int nt = 0; nt < 4; nt++) {
            const int kk = c + 4 * l16 + nt;
            const bool valid = (kk > irow) && (kk <= irow + 1024);
            pk[nt] = valid ? (__bf16)exp2f(s[mt][nt][r] * ES) : (__bf16)0.0f;
          }
        }
        *(bf16x4*)(myP + (mt * 16 + quad * 4 + r) * 72 + 4 * l16) = pk;
      }
    }
    asm volatile("s_waitcnt lgkmcnt(0)" ::: "memory");
#pragma unroll
    for (int kc = 0; kc < 2; kc++) {
      bf16x8 pf0 = *(const bf16x8*)(myP + (l16) * 72 + kc * 32 + quad * 8);
      bf16x8 pf1 = *(const bf16x8*)(myP + (16 + l16) * 72 + kc * 32 + quad * 8);
      lac[0] = __builtin_amdgcn_mfma_f32_16x16x32_bf16(pf0, ones, lac[0], 0, 0, 0);
      lac[1] = __builtin_amdgcn_mfma_f32_16x16x32_bf16(pf1, ones, lac[1], 0, 0, 0);
#pragma unroll
      for (int dt = 0; dt < 8; dt++) {
        bf16x8 vf = *(const bf16x8*)(sV + (dt * 16 + l16) * 64 + ((kc * 4 + quad) ^ xsw) * 8);
        o[dt][0] = __builtin_amdgcn_mfma_f32_16x16x32_bf16(pf0, vf, o[dt][0], 0, 0, 0);
        o[dt][1] = __builtin_amdgcn_mfma_f32_16x16x32_bf16(pf1, vf, o[dt][1], 0, 0, 0);
      }
    }
    __syncthreads();  // C: all waves done reading sV
    if (ci < 16) {
#pragma unroll
      for (int j = 0; j < 4; j++) gll16(vb + (size_t)(c + 64) + vgo[j], vls + j * 512);
    }
  }

  float inv[2][4];
#pragma unroll
  for (int mt = 0; mt < 2; mt++)
#pragma unroll
    for (int r = 0; r < 4; r++) inv[mt][r] = 1.0f / lac[mt][r];
#pragma unroll
  for (int dt = 0; dt < 8; dt++)
#pragma unroll
    for (int mt = 0; mt < 2; mt++)
#pragma unroll
      for (int r = 0; r < 4; r++)
        out[(size_t)(b * QL + i0 + mt * 16 + quad * 4 + r) * (NH * HD) + h * HD + dt * 16 + l16] =
            (__bf16)(o[dt][mt][r] * inv[mt][r]);
}

// ---------------------------------------------------------------------------
extern "C" void kernel_launch(void* const* d_in, const int* in_sizes, int n_in,
                              void* d_out, int out_size, void* d_ws, size_t ws_size,
                              hipStream_t stream) {
  const float* hidden = (const float*)d_in[0];
  const float* wq = (const float*)d_in[1];
  const float* wk = (const float*)d_in[2];
  const float* wv = (const float*)d_in[3];
  const float* wo = (const float*)d_in[4];
  const float* kcache = (const float*)d_in[5];
  const float* vcache = (const float*)d_in[6];
  (void)in_sizes; (void)n_in; (void)out_size; (void)ws_size;

  char* w = (char*)d_ws;
  __bf16* hid_b  = (__bf16*)(w);
  __bf16* wqkvT  = (__bf16*)(w + 33554432ULL);
  __bf16* qkv    = (__bf16*)(w + 83886080ULL);
  __bf16* k_all  = (__bf16*)(w + 134217728ULL);
  __bf16* v_allT = (__bf16*)(w + 150994944ULL);
  __bf16* attn   = hid_b;   // hidden dead after QKV GEMM
  __bf16* woT    = wqkvT;   // wqkvT dead after QKV GEMM

  cast_plain<<<16384, 256, 0, stream>>>(hidden, hid_b, 4194304);
  transpose_cast<<<dim3(64, 64), 256, 0, stream>>>(wq, wqkvT, 4096, 4096);
  transpose_cast<<<dim3(16, 64), 256, 0, stream>>>(wk, wqkvT + 16777216ULL, 4096, 1024);
  transpose_cast<<<dim3(16, 64), 256, 0, stream>>>(wv, wqkvT + 20971520ULL, 4096, 1024);
  gemm128x256<1><<<dim3(768), 512, 0, stream>>>(hid_b, wqkvT, (void*)qkv, 4096, 6144, 4096);
  rope_kernel<<<40960, 256, 0, stream>>>(qkv);
  kv_build_k<<<4096, 256, 0, stream>>>(kcache, qkv, k_all);
  kv_build_vT<<<1024, 256, 0, stream>>>(vcache, qkv, v_allT);
  attn_kernel<<<1024, 256, 0, stream>>>(qkv, k_all, v_allT, attn);
  transpose_cast<<<dim3(64, 64), 256, 0, stream>>>(wo, woT, 4096, 4096);
  gemm128x256<0><<<dim3(512), 512, 0, stream>>>(attn, woT, d_out, 4096, 4096, 4096);
}

// Round 3
// 765.246 us; speedup vs baseline: 1.0493x; 1.0493x over previous
//
#include <hip/hip_runtime.h>
#include <hip/hip_bf16.h>

typedef __bf16 bf16x8 __attribute__((ext_vector_type(8)));
typedef __bf16 bf16x4 __attribute__((ext_vector_type(4)));
typedef float  f32x4  __attribute__((ext_vector_type(4)));

#define QL 1024
#define NH 32
#define NKV 8
#define HD 128
#define KVLEN 2048
#define QKV_LD 6144

// async global->LDS, 16B per lane. LDS dest = wave-uniform base + lane*16;
// we pass per-lane ptr = base + lane*16 so both interpretations agree.
// Global side addressing is per-lane (gather is allowed on the global side).
typedef const __attribute__((address_space(1))) void gv_t;
typedef __attribute__((address_space(3))) void lv_t;
__device__ __forceinline__ void gll16(const void* g, void* l) {
  __builtin_amdgcn_global_load_lds((gv_t*)g, (lv_t*)l, 16, 0, 0);
}

// ---------------------------------------------------------------------------
// fp32 -> bf16 plain cast
// ---------------------------------------------------------------------------
__global__ __launch_bounds__(256) void cast_plain(const float* __restrict__ in,
                                                  __bf16* __restrict__ out, int n4) {
  int i = blockIdx.x * 256 + threadIdx.x;
  if (i >= n4) return;
  float4 v = ((const float4*)in)[i];
  bf16x4 o;
  o[0] = (__bf16)v.x; o[1] = (__bf16)v.y; o[2] = (__bf16)v.z; o[3] = (__bf16)v.w;
  ((bf16x4*)out)[i] = o;
}

// ---------------------------------------------------------------------------
// fp32 (R x C) -> bf16 (C x R) transpose-cast
// ---------------------------------------------------------------------------
__global__ __launch_bounds__(256) void transpose_cast(const float* __restrict__ in,
                                                      __bf16* __restrict__ out,
                                                      int R, int C) {
  __shared__ __bf16 tile[64][65];
  int r0 = blockIdx.y * 64, c0 = blockIdx.x * 64;
  int t = threadIdx.x;
  int tr = t >> 4, tc = (t & 15) * 4;
#pragma unroll
  for (int pass = 0; pass < 4; pass++) {
    int r = pass * 16 + tr;
    float4 v = *(const float4*)(in + (size_t)(r0 + r) * C + c0 + tc);
    tile[r][tc + 0] = (__bf16)v.x;
    tile[r][tc + 1] = (__bf16)v.y;
    tile[r][tc + 2] = (__bf16)v.z;
    tile[r][tc + 3] = (__bf16)v.w;
  }
  __syncthreads();
#pragma unroll
  for (int pass = 0; pass < 4; pass++) {
    int cc = pass * 16 + tr;
    bf16x4 o;
#pragma unroll
    for (int j = 0; j < 4; j++) o[j] = tile[tc + j][cc];
    *(bf16x4*)(out + (size_t)(c0 + cc) * R + r0 + tc) = o;
  }
}

// ---------------------------------------------------------------------------
// C[M,N] = A[M,K] @ Bt[N,K]^T -- 256x256 tile (WO GEMM: grid 256 = 1 exact
// round, best-measured config for 4096^3). 8 waves (2Mx4N), BK=32, depth-4
// LDS ring, counted vmcnt(8), T2 XOR-quad swizzle, T5 setprio.
// ---------------------------------------------------------------------------
template <int OUT_BF16>
__global__ __launch_bounds__(512, 2) void gemm256(const __bf16* __restrict__ A,
                                                  const __bf16* __restrict__ Bt,
                                                  void* __restrict__ Cout,
                                                  int M, int N, int K) {
  __shared__ __attribute__((aligned(16))) __bf16 sA[4][8192];   // 4 x (256 rows x 32)
  __shared__ __attribute__((aligned(16))) __bf16 sB[4][8192];
  const int tid = threadIdx.x;
  const int lane = tid & 63;
  const int wave = tid >> 6;            // 0..7
  const int wm = wave >> 2, wn = wave & 3;
  const int quad = lane >> 4, l16 = lane & 15;

  // XCD-aware bijective swizzle (grid sizes are multiples of 8)
  const int nwg = gridDim.x;
  const int id = blockIdx.x;
  const int swz = (id & 7) * (nwg >> 3) + (id >> 3);
  const int gx = N >> 8;
  const int by = swz / gx, bx = swz - by * gx;
  const int row0 = by * 256, col0 = bx * 256;

  const int qsel = (tid & 3) ^ ((tid >> 3) & 3);
  const __bf16* pA0 = A + (size_t)(row0 + (tid >> 2)) * K + qsel * 8;
  const __bf16* pA1 = pA0 + (size_t)128 * K;
  const __bf16* pB0 = Bt + (size_t)(col0 + (tid >> 2)) * K + qsel * 8;
  const __bf16* pB1 = pB0 + (size_t)128 * K;

  const int xsw = (l16 >> 1) & 3;
  const int aoff = (wm * 128 + l16) * 32 + (quad ^ xsw) * 8;
  const int boff = (wn * 64 + l16) * 32 + (quad ^ xsw) * 8;

  f32x4 acc[8][4];
#pragma unroll
  for (int mt = 0; mt < 8; mt++)
#pragma unroll
    for (int nt = 0; nt < 4; nt++) acc[mt][nt] = (f32x4){0.f, 0.f, 0.f, 0.f};

  const int nT = K >> 5;

  // prologue: stage tiles 0,1,2 (12 loads in flight), wait tile 0 (leave 8)
  for (int pt = 0; pt < 3; ++pt) {
    __bf16* dA = &sA[pt][0];
    __bf16* dB = &sB[pt][0];
    gll16(pA0, dA + tid * 8);
    gll16(pA1, dA + 4096 + tid * 8);
    gll16(pB0, dB + tid * 8);
    gll16(pB1, dB + 4096 + tid * 8);
    pA0 += 32; pA1 += 32; pB0 += 32; pB1 += 32;
  }
  asm volatile("s_waitcnt vmcnt(8)" ::: "memory");
  __builtin_amdgcn_s_barrier();

  for (int t = 0; t < nT; ++t) {
    const int bt = t & 3;
    const bool st = (t + 3 < nT);
    const __bf16* Ab = &sA[bt][aoff];
    const __bf16* Bb = &sB[bt][boff];
    __bf16* dA = &sA[(t + 3) & 3][0];
    __bf16* dB = &sB[(t + 3) & 3][0];
    bf16x8 a[4], b[4];

    // ---- phase 1: quadrant mt0-3 x nt0-3 ----
#pragma unroll
    for (int i = 0; i < 4; ++i) a[i] = *(const bf16x8*)(Ab + i * 512);
#pragma unroll
    for (int i = 0; i < 4; ++i) b[i] = *(const bf16x8*)(Bb + i * 512);
    if (st) {
      gll16(pA0, dA + tid * 8);
      gll16(pA1, dA + 4096 + tid * 8);
    }
    asm volatile("" ::: "memory");
    __builtin_amdgcn_s_barrier();
    __builtin_amdgcn_s_setprio(1);
#pragma unroll
    for (int mt = 0; mt < 4; ++mt)
#pragma unroll
      for (int nt = 0; nt < 4; ++nt)
        acc[mt][nt] = __builtin_amdgcn_mfma_f32_16x16x32_bf16(a[mt], b[nt], acc[mt][nt], 0, 0, 0);
    __builtin_amdgcn_s_setprio(0);
    __builtin_amdgcn_s_barrier();

    // ---- phase 2: quadrant mt4-7 x nt0-3 ----
#pragma unroll
    for (int i = 0; i < 4; ++i) a[i] = *(const bf16x8*)(Ab + (4 + i) * 512);
    if (st) {
      gll16(pB0, dB + tid * 8);
      gll16(pB1, dB + 4096 + tid * 8);
      pA0 += 32; pA1 += 32; pB0 += 32; pB1 += 32;
    }
    if (t + 3 < nT) {
      asm volatile("s_waitcnt vmcnt(8)" ::: "memory");
    } else if (t + 2 < nT) {
      asm volatile("s_waitcnt vmcnt(4)" ::: "memory");
    } else if (t + 1 < nT) {
      asm volatile("s_waitcnt vmcnt(0)" ::: "memory");
    }
    __builtin_amdgcn_s_barrier();
    __builtin_amdgcn_s_setprio(1);
#pragma unroll
    for (int mt = 0; mt < 4; ++mt)
#pragma unroll
      for (int nt = 0; nt < 4; ++nt)
        acc[4 + mt][nt] = __builtin_amdgcn_mfma_f32_16x16x32_bf16(a[mt], b[nt], acc[4 + mt][nt], 0, 0, 0);
    __builtin_amdgcn_s_setprio(0);
    __builtin_amdgcn_s_barrier();
  }

#pragma unroll
  for (int mt = 0; mt < 8; ++mt) {
#pragma unroll
    for (int r = 0; r < 4; ++r) {
      const int grow = row0 + wm * 128 + mt * 16 + quad * 4 + r;
#pragma unroll
      for (int nt = 0; nt < 4; ++nt) {
        const int gcol = col0 + wn * 64 + nt * 16 + l16;
        float v = acc[mt][nt][r];
        if (OUT_BF16)
          ((__bf16*)Cout)[(size_t)grow * N + gcol] = (__bf16)v;
        else
          ((float*)Cout)[(size_t)grow * N + gcol] = v;
      }
    }
  }
}

// ---------------------------------------------------------------------------
// C[M,N] = A[M,K] @ Bt[N,K]^T -- 128x256 tile (QKV GEMM: grid 768 = 3 exact
// rounds for 4096x6144). BK=64, depth-2 dbuf at k-half granularity, counted
// vmcnt(6), same swizzle family. (Best-measured config for the QKV shape.)
// ---------------------------------------------------------------------------
template <int OUT_BF16>
__global__ __launch_bounds__(512, 2) void gemm128x256(const __bf16* __restrict__ A,
                                                      const __bf16* __restrict__ Bt,
                                                      void* __restrict__ Cout,
                                                      int M, int N, int K) {
  __shared__ __attribute__((aligned(16))) __bf16 sA[2][8192];    // [buf][kh*4096 + r*32 + p*8]
  __shared__ __attribute__((aligned(16))) __bf16 sB[2][16384];   // [buf][kh*8192 + n*32 + p*8]
  const int tid = threadIdx.x;
  const int lane = tid & 63;
  const int wave = tid >> 6;
  const int wm = wave >> 2, wn = wave & 3;   // 2M x 4N
  const int quad = lane >> 4, l16 = lane & 15;

  const int nwg = gridDim.x;
  const int id = blockIdx.x;
  int swz = (id & 7) * (nwg >> 3) + (id >> 3);
  const int gx = N >> 8;
  int by = swz / gx;
  int bx = swz - by * gx;
  if (by & 1) bx = gx - 1 - bx;
  const int row0 = by * 128, col0 = bx * 256;

  const int qsel = (tid & 3) ^ ((tid >> 3) & 3);
  const __bf16* gA  = A  + (size_t)(row0 + (tid >> 2)) * K + qsel * 8;
  const __bf16* gB0 = Bt + (size_t)(col0 + (tid >> 2)) * K + qsel * 8;
  const __bf16* gB1 = gB0 + (size_t)128 * K;

  const int xq = (quad ^ ((l16 >> 1) & 3)) * 8;
  const int abase = (wm * 64 + l16) * 32 + xq;   // + kc*4096 + mt*512
  const int bbase = (wn * 64 + l16) * 32 + xq;   // + kc*8192 + nt*512

  f32x4 acc[4][4];
#pragma unroll
  for (int mt = 0; mt < 4; mt++)
#pragma unroll
    for (int nt = 0; nt < 4; nt++) acc[mt][nt] = (f32x4){0.f, 0.f, 0.f, 0.f};

  const int nT = K >> 6;

#define STAGE_A(t_, kh_)                                                        \
  gll16(gA + (size_t)(t_)*64 + (kh_)*32, &sA[(t_) & 1][(kh_)*4096] + tid * 8)
#define STAGE_B(t_, kh_)                                                        \
  do {                                                                          \
    __bf16* d_ = &sB[(t_) & 1][(kh_)*8192];                                     \
    gll16(gB0 + (size_t)(t_)*64 + (kh_)*32, d_ + tid * 8);                      \
    gll16(gB1 + (size_t)(t_)*64 + (kh_)*32, d_ + 4096 + tid * 8);               \
  } while (0)

  STAGE_A(0, 0); STAGE_B(0, 0);
  STAGE_A(0, 1); STAGE_B(0, 1);
  if (nT > 1) { STAGE_A(1, 0); STAGE_B(1, 0); }
  asm volatile("s_waitcnt vmcnt(6)" ::: "memory");
  __builtin_amdgcn_s_barrier();

  for (int t = 0; t < nT; ++t) {
    const __bf16* Ab = &sA[t & 1][0];
    const __bf16* Bb = &sB[t & 1][0];
    bf16x8 af[4], bfr[4];

    // ---- phase 1 (kc=0) ----
#pragma unroll
    for (int i = 0; i < 4; ++i) af[i]  = *(const bf16x8*)(Ab + abase + i * 512);
#pragma unroll
    for (int i = 0; i < 4; ++i) bfr[i] = *(const bf16x8*)(Bb + bbase + i * 512);
    if (t + 1 < nT) {
      STAGE_A(t + 1, 1); STAGE_B(t + 1, 1);
      asm volatile("s_waitcnt vmcnt(6)" ::: "memory");
    } else {
      asm volatile("s_waitcnt vmcnt(0)" ::: "memory");
    }
    __builtin_amdgcn_s_barrier();
    __builtin_amdgcn_s_setprio(1);
#pragma unroll
    for (int mt = 0; mt < 4; ++mt)
#pragma unroll
      for (int nt = 0; nt < 4; ++nt)
        acc[mt][nt] = __builtin_amdgcn_mfma_f32_16x16x32_bf16(af[mt], bfr[nt], acc[mt][nt], 0, 0, 0);
    __builtin_amdgcn_s_setprio(0);

    // ---- phase 2 (kc=1) ----
#pragma unroll
    for (int i = 0; i < 4; ++i) af[i]  = *(const bf16x8*)(Ab + 4096 + abase + i * 512);
#pragma unroll
    for (int i = 0; i < 4; ++i) bfr[i] = *(const bf16x8*)(Bb + 8192 + bbase + i * 512);
    if (t + 2 < nT) {
      STAGE_A(t + 2, 0); STAGE_B(t + 2, 0);
      asm volatile("s_waitcnt vmcnt(6)" ::: "memory");
    } else if (t + 1 < nT) {
      asm volatile("s_waitcnt vmcnt(3)" ::: "memory");
    } else {
      asm volatile("" ::: "memory");
    }
    __builtin_amdgcn_s_barrier();
    __builtin_amdgcn_s_setprio(1);
#pragma unroll
    for (int mt = 0; mt < 4; ++mt)
#pragma unroll
      for (int nt = 0; nt < 4; ++nt)
        acc[mt][nt] = __builtin_amdgcn_mfma_f32_16x16x32_bf16(af[mt], bfr[nt], acc[mt][nt], 0, 0, 0);
    __builtin_amdgcn_s_setprio(0);
  }
#undef STAGE_A
#undef STAGE_B

#pragma unroll
  for (int mt = 0; mt < 4; ++mt) {
#pragma unroll
    for (int r = 0; r < 4; ++r) {
      const int grow = row0 + wm * 64 + mt * 16 + quad * 4 + r;
#pragma unroll
      for (int nt = 0; nt < 4; ++nt) {
        const int gcol = col0 + wn * 64 + nt * 16 + l16;
        float v = acc[mt][nt][r];
        if (OUT_BF16)
          ((__bf16*)Cout)[(size_t)grow * N + gcol] = (__bf16)v;
        else
          ((float*)Cout)[(size_t)grow * N + gcol] = v;
      }
    }
  }
}

// ---------------------------------------------------------------------------
// RoPE in-place on qkv. One block per token row; each thread computes sincos
// ONCE (angle depends only on (pos, m)) and applies it to 10 heads.
// 1.05M threads / 1 sincos each vs previous 10.5M sincos.
// ---------------------------------------------------------------------------
__global__ __launch_bounds__(256) void rope_kernel(__bf16* __restrict__ qkv) {
  int t = blockIdx.x;               // token row 0..4095
  int tid = threadIdx.x;
  int hg = tid >> 6;                // 0..3 (wave = head-group)
  int m = tid & 63;
  int i = t & (QL - 1);
  float pos = (float)(1024 + i);
  float ang = pos * exp2f(-(float)m * 0.31143075889569403f);
  float c = cosf(ang), sn = sinf(ang);
  size_t row = (size_t)t * QKV_LD;
#pragma unroll
  for (int u = 0; u < 10; u++) {
    int head = hg + u * 4;          // 0..39 (q heads 0-31, k heads 32-39)
    size_t base = row + head * HD;
    float x0 = (float)qkv[base + m];
    float x1 = (float)qkv[base + 64 + m];
    qkv[base + m]      = (__bf16)(x0 * c - x1 * sn);
    qkv[base + 64 + m] = (__bf16)(x1 * c + x0 * sn);
  }
}

// ---------------------------------------------------------------------------
// k_all[b][kvh][p][d]
// ---------------------------------------------------------------------------
__global__ __launch_bounds__(256) void kv_build_k(const float* __restrict__ kcache,
                                                  const __bf16* __restrict__ qkv,
                                                  __bf16* __restrict__ k_all) {
  int idx = blockIdx.x * 256 + threadIdx.x;
  int d8 = (idx & 15) * 8;
  int p = (idx >> 4) & (KVLEN - 1);
  int bk = idx >> 15;
  int b = bk >> 3, kvh = bk & 7;
  __bf16* dst = k_all + ((size_t)bk * KVLEN + p) * HD + d8;
  if (p < 1024) {
    const float* src = kcache + ((size_t)(b * KVLEN + p) * NKV + kvh) * HD + d8;
    bf16x8 o;
#pragma unroll
    for (int j = 0; j < 8; j++) o[j] = (__bf16)src[j];
    *(bf16x8*)dst = o;
  } else {
    const __bf16* src = qkv + (size_t)(b * QL + p - 1024) * QKV_LD + 4096 + kvh * HD + d8;
    *(bf16x8*)dst = *(const bf16x8*)src;
  }
}

// ---------------------------------------------------------------------------
// v_allT[b][kvh][d][p]
// ---------------------------------------------------------------------------
__global__ __launch_bounds__(256) void kv_build_vT(const float* __restrict__ vcache,
                                                   const __bf16* __restrict__ qkv,
                                                   __bf16* __restrict__ v_allT) {
  __shared__ __bf16 tile[64][130];
  int blk = blockIdx.x;
  int pt = blk & 31, bk = blk >> 5;
  int b = bk >> 3, kvh = bk & 7;
  int p0 = pt * 64;
  int t = threadIdx.x;
  int lr = t >> 4, d8 = (t & 15) * 8;
#pragma unroll
  for (int pass = 0; pass < 4; pass++) {
    int pl = pass * 16 + lr;
    int p = p0 + pl;
    if (p < 1024) {
      const float* src = vcache + ((size_t)(b * KVLEN + p) * NKV + kvh) * HD + d8;
#pragma unroll
      for (int j = 0; j < 8; j++) tile[pl][d8 + j] = (__bf16)src[j];
    } else {
      const __bf16* src = qkv + (size_t)(b * QL + p - 1024) * QKV_LD + 5120 + kvh * HD + d8;
      bf16x8 v = *(const bf16x8*)src;
#pragma unroll
      for (int j = 0; j < 8; j++) tile[pl][d8 + j] = v[j];
    }
  }
  __syncthreads();
#pragma unroll
  for (int pass = 0; pass < 4; pass++) {
    int d = (t >> 3) + pass * 32;
    int ps = (t & 7) * 8;
    bf16x8 o;
#pragma unroll
    for (int j = 0; j < 8; j++) o[j] = tile[ps + j][d];
    *(bf16x8*)(v_allT + ((size_t)bk * HD + d) * KVLEN + p0 + ps) = o;
  }
}

// ---------------------------------------------------------------------------
// Flash attention v3: K/V staged once per block in LDS, shared by 4 GQA waves,
// async gll16 prefetch pipelined across chunks, XOR-swizzled LDS slots.
// ---------------------------------------------------------------------------
__global__ __launch_bounds__(256) void attn_kernel(const __bf16* __restrict__ qkv,
                                                   const __bf16* __restrict__ k_all,
                                                   const __bf16* __restrict__ v_allT,
                                                   __bf16* __restrict__ out) {
  __shared__ __attribute__((aligned(16))) __bf16 sK[64 * 128];   // [key][d], slot-swizzled
  __shared__ __attribute__((aligned(16))) __bf16 sV[128 * 64];   // [d][key], slot-swizzled
  __shared__ __attribute__((aligned(16))) __bf16 sP[4][32 * 72];
  const int tid = threadIdx.x;
  const int lane = tid & 63;
  const int wave = tid >> 6;
  const int quad = lane >> 4, l16 = lane & 15;
  const int bid = blockIdx.x;
  const int b = bid & 3;
  const int kvh = (bid >> 2) & 7;
  const int qt = bid >> 5;
  const int h = kvh * 4 + wave;
  const int i0 = qt * 32;

  const __bf16* kb = k_all + (size_t)(b * NKV + kvh) * KVLEN * HD;
  const __bf16* vb = v_allT + (size_t)(b * NKV + kvh) * HD * KVLEN;

  bf16x8 qf[2][4];
#pragma unroll
  for (int mt = 0; mt < 2; mt++) {
    const __bf16* qb = qkv + (size_t)(b * QL + i0 + mt * 16 + l16) * QKV_LD + h * HD + quad * 8;
#pragma unroll
    for (int kc = 0; kc < 4; kc++) qf[mt][kc] = *(const bf16x8*)(qb + kc * 32);
  }

  int kgo[4], vgo[4];
#pragma unroll
  for (int j = 0; j < 4; j++) {
    int g = wave * 4 + j;
    kgo[j] = (g * 4 + quad) * HD + (l16 ^ (g & 7)) * 8;
    int d = g * 8 + (lane >> 3);
    vgo[j] = d * KVLEN + ((lane & 7) ^ ((lane >> 3) & 7)) * 8;
  }
  __bf16* kls = sK + (wave * 4) * 512 + lane * 8;  // +j*512
  __bf16* vls = sV + (wave * 4) * 512 + lane * 8;

  f32x4 o[8][2];
#pragma unroll
  for (int dt = 0; dt < 8; dt++)
#pragma unroll
    for (int mt = 0; mt < 2; mt++) o[dt][mt] = (f32x4){0.f, 0.f, 0.f, 0.f};
  f32x4 lac[2];
  lac[0] = (f32x4){0.f, 0.f, 0.f, 0.f};
  lac[1] = (f32x4){0.f, 0.f, 0.f, 0.f};

  bf16x8 ones;
#pragma unroll
  for (int j = 0; j < 8; j++) ones[j] = (__bf16)1.0f;

  __bf16* myP = &sP[wave][0];
  const float ES = 0.12751744f;  // (1/sqrt(128)) * log2(e)

  const int cs = (i0 + 1) & ~63;
  const int xsw = l16 & 7;

#pragma unroll
  for (int j = 0; j < 4; j++) gll16(kb + (size_t)cs * HD + kgo[j], kls + j * 512);
#pragma unroll
  for (int j = 0; j < 4; j++) gll16(vb + (size_t)cs + vgo[j], vls + j * 512);

  for (int ci = 0; ci < 17; ci++) {
    const int c = cs + ci * 64;
    __syncthreads();  // A: chunk ci staged; sV safe from prev iter
    f32x4 s[2][4];
#pragma unroll
    for (int nt = 0; nt < 4; nt++) {
      s[0][nt] = (f32x4){0.f, 0.f, 0.f, 0.f};
      s[1][nt] = (f32x4){0.f, 0.f, 0.f, 0.f};
      const __bf16* kp = sK + (4 * l16 + nt) * HD;
#pragma unroll
      for (int kc = 0; kc < 4; kc++) {
        bf16x8 kf = *(const bf16x8*)(kp + ((4 * kc + quad) ^ xsw) * 8);
        s[0][nt] = __builtin_amdgcn_mfma_f32_16x16x32_bf16(qf[0][kc], kf, s[0][nt], 0, 0, 0);
        s[1][nt] = __builtin_amdgcn_mfma_f32_16x16x32_bf16(qf[1][kc], kf, s[1][nt], 0, 0, 0);
      }
    }
    __syncthreads();  // B: all waves done reading sK
    if (ci < 16) {
#pragma unroll
      for (int j = 0; j < 4; j++) gll16(kb + (size_t)(c + 64) * HD + kgo[j], kls + j * 512);
    }
    const bool full = (c >= i0 + 32) && (c <= i0 + 961);
#pragma unroll
    for (int mt = 0; mt < 2; mt++) {
#pragma unroll
      for (int r = 0; r < 4; r++) {
        bf16x4 pk;
        if (full) {
#pragma unroll
          for (int nt = 0; nt < 4; nt++) pk[nt] = (__bf16)exp2f(s[mt][nt][r] * ES);
        } else {
          const int irow = i0 + mt * 16 + quad * 4 + r;
#pragma unroll
          for (int nt = 0; nt < 4; nt++) {
            const int kk = c + 4 * l16 + nt;
            const bool valid = (kk > irow) && (kk <= irow + 1024);
            pk[nt] = valid ? (__bf16)exp2f(s[mt][nt][r] * ES) : (__bf16)0.0f;
          }
        }
        *(bf16x4*)(myP + (mt * 16 + quad * 4 + r) * 72 + 4 * l16) = pk;
      }
    }
    asm volatile("s_waitcnt lgkmcnt(0)" ::: "memory");
#pragma unroll
    for (int kc = 0; kc < 2; kc++) {
      bf16x8 pf0 = *(const bf16x8*)(myP + (l16) * 72 + kc * 32 + quad * 8);
      bf16x8 pf1 = *(const bf16x8*)(myP + (16 + l16) * 72 + kc * 32 + quad * 8);
      lac[0] = __builtin_amdgcn_mfma_f32_16x16x32_bf16(pf0, ones, lac[0], 0, 0, 0);
      lac[1] = __builtin_amdgcn_mfma_f32_16x16x32_bf16(pf1, ones, lac[1], 0, 0, 0);
#pragma unroll
      for (int dt = 0; dt < 8; dt++) {
        bf16x8 vf = *(const bf16x8*)(sV + (dt * 16 + l16) * 64 + ((kc * 4 + quad) ^ xsw) * 8);
        o[dt][0] = __builtin_amdgcn_mfma_f32_16x16x32_bf16(pf0, vf, o[dt][0], 0, 0, 0);
        o[dt][1] = __builtin_amdgcn_mfma_f32_16x16x32_bf16(pf1, vf, o[dt][1], 0, 0, 0);
      }
    }
    __syncthreads();  // C: all waves done reading sV
    if (ci < 16) {
#pragma unroll
      for (int j = 0; j < 4; j++) gll16(vb + (size_t)(c + 64) + vgo[j], vls + j * 512);
    }
  }

  float inv[2][4];
#pragma unroll
  for (int mt = 0; mt < 2; mt++)
#pragma unroll
    for (int r = 0; r < 4; r++) inv[mt][r] = 1.0f / lac[mt][r];
#pragma unroll
  for (int dt = 0; dt < 8; dt++)
#pragma unroll
    for (int mt = 0; mt < 2; mt++)
#pragma unroll
      for (int r = 0; r < 4; r++)
        out[(size_t)(b * QL + i0 + mt * 16 + quad * 4 + r) * (NH * HD) + h * HD + dt * 16 + l16] =
            (__bf16)(o[dt][mt][r] * inv[mt][r]);
}

// ---------------------------------------------------------------------------
extern "C" void kernel_launch(void* const* d_in, const int* in_sizes, int n_in,
                              void* d_out, int out_size, void* d_ws, size_t ws_size,
                              hipStream_t stream) {
  const float* hidden = (const float*)d_in[0];
  const float* wq = (const float*)d_in[1];
  const float* wk = (const float*)d_in[2];
  const float* wv = (const float*)d_in[3];
  const float* wo = (const float*)d_in[4];
  const float* kcache = (const float*)d_in[5];
  const float* vcache = (const float*)d_in[6];
  (void)in_sizes; (void)n_in; (void)out_size; (void)ws_size;

  char* w = (char*)d_ws;
  __bf16* hid_b  = (__bf16*)(w);
  __bf16* wqkvT  = (__bf16*)(w + 33554432ULL);
  __bf16* qkv    = (__bf16*)(w + 83886080ULL);
  __bf16* k_all  = (__bf16*)(w + 134217728ULL);
  __bf16* v_allT = (__bf16*)(w + 150994944ULL);
  __bf16* attn   = hid_b;   // hidden dead after QKV GEMM
  __bf16* woT    = wqkvT;   // wqkvT dead after QKV GEMM

  cast_plain<<<16384, 256, 0, stream>>>(hidden, hid_b, 4194304);
  transpose_cast<<<dim3(64, 64), 256, 0, stream>>>(wq, wqkvT, 4096, 4096);
  transpose_cast<<<dim3(16, 64), 256, 0, stream>>>(wk, wqkvT + 16777216ULL, 4096, 1024);
  transpose_cast<<<dim3(16, 64), 256, 0, stream>>>(wv, wqkvT + 20971520ULL, 4096, 1024);
  gemm128x256<1><<<dim3(768), 512, 0, stream>>>(hid_b, wqkvT, (void*)qkv, 4096, 6144, 4096);
  rope_kernel<<<4096, 256, 0, stream>>>(qkv);
  kv_build_k<<<4096, 256, 0, stream>>>(kcache, qkv, k_all);
  kv_build_vT<<<1024, 256, 0, stream>>>(vcache, qkv, v_allT);
  attn_kernel<<<1024, 256, 0, stream>>>(qkv, k_all, v_allT, attn);
  transpose_cast<<<dim3(64, 64), 256, 0, stream>>>(wo, woT, 4096, 4096);
  gemm256<0><<<dim3(256), 512, 0, stream>>>(attn, woT, d_out, 4096, 4096, 4096);
}